// Round 6
// baseline (189.312 us; speedup 1.0000x reference)
//
#include <hip/hip_runtime.h>
#include <math.h>

// DigitCaps dynamic routing, MFMA version, round 6.
// u[b,n,cl] = sum_j x[b,n,j] W[n,j,cl] per-n on v_mfma_f32_16x16x16f16
//   (M=16: one capsule c's 16 l, N=16: batch, K=16; j=8 real).
// R6 vs R5: R5's live state (~140-160 regs incl 40 AGPRs, unified file)
// capped occupancy at 2 waves/SIMD -> latency-bound (~36us/pass vs ~5us
// issue-bound). Changes:
//  - Block = 16 batches x 4 waves, waves split N (6 n each); end-of-kernel
//    LDS tree-reduce (3 slots, stride 164 floats: 2-way banks = free);
//    only wave 0 writes partials. Partials 31.5 -> 15.7 MB/pass.
//  - Register diet (~112 total incl AGPRs) + __launch_bounds__(256,4):
//    4 waves/SIMD, 2x R5's wave supply; grid (192,8)=1536 blocks.
//  - Softmax denominator summed as a TREE (strict-fp serial chain removed).
//  - Keeps R5's two-MFMA-group trick: u never stored; routing weight w[b,c]
//    (per-lane == B-fragment column) folded into B of the second MFMA group.
//  - MODE 0 packs two n per MFMA (k=0..7 <- n, k=8..15 <- n+1).

namespace {
constexpr int B_   = 128;
constexpr int N_   = 4608;
constexpr int C_   = 10;
constexpr int L_   = 16;
constexpr int CL   = C_ * L_;            // 160
constexpr int TILE_W = 6;                // n per wave
constexpr int TILE_B = 4 * TILE_W;       // 24 n per block
constexpr int NCHK = N_ / TILE_B;        // 192 partial chunks (grid.x)
constexpr int BCL  = B_ * CL;            // 20480
constexpr int RED_G = 16;
constexpr int RED_K = NCHK / RED_G;      // 12
constexpr int WBLK = (N_ * CL) / 256;    // 2880 blocks: W pack
constexpr int XBLK = (B_ * N_) / 256;    // 2304 blocks: x convert
constexpr int PADL = 164;                // padded row stride (floats) in LDS
}

typedef _Float16 h2  __attribute__((ext_vector_type(2)));
typedef _Float16 v4h __attribute__((ext_vector_type(4)));
typedef _Float16 v8h __attribute__((ext_vector_type(8)));
typedef float    v4f __attribute__((ext_vector_type(4)));

__device__ inline h2 pkrtz(float a, float b) {
  return __builtin_bit_cast(h2, __builtin_amdgcn_cvt_pkrtz(a, b));
}

#if defined(__has_builtin)
#if __has_builtin(__builtin_amdgcn_fdot2)
#define HAVE_FDOT2 1
#endif
#endif

__device__ inline float fdot2(h2 a, h2 b, float c) {
#ifdef HAVE_FDOT2
  return __builtin_amdgcn_fdot2(a, b, c, false);
#else
  return c + (float)a[0] * (float)b[0] + (float)a[1] * (float)b[1];
#endif
}

// W [N][8][160] f32 -> Wt [N][160][8] f16 (transpose j<->cl, pack)
// x [B][N][8]  f32 -> xh [B][N][8]  f16 (straight convert)
__global__ __launch_bounds__(256)
void conv_pack(const float* __restrict__ W, const float* __restrict__ x,
               v8h* __restrict__ Wt, v8h* __restrict__ xh)
{
  if ((int)blockIdx.x < WBLK) {
    const int t  = blockIdx.x * 256 + threadIdx.x;     // (n, cl)
    const int n  = t / CL, cl = t % CL;
    const float* p = W + (size_t)n * (8 * CL) + cl;
    v8h o;
#pragma unroll
    for (int j = 0; j < 8; ++j) o[j] = (_Float16)p[j * CL];
    Wt[t] = o;
  } else {
    const int t = ((int)blockIdx.x - WBLK) * 256 + threadIdx.x; // 8-float chunk
    const float4 a = ((const float4*)x)[(size_t)t * 2 + 0];
    const float4 b = ((const float4*)x)[(size_t)t * 2 + 1];
    v8h o = { (_Float16)a.x, (_Float16)a.y, (_Float16)a.z, (_Float16)a.w,
              (_Float16)b.x, (_Float16)b.y, (_Float16)b.z, (_Float16)b.w };
    xh[t] = o;
  }
}

// MODE 0: uniform coupling (1/10 folded into reduce_b scale)
// MODE 1: logits t = u.v0      MODE 2: logits t = u.(v0+v1)
template<int MODE>
__global__ __launch_bounds__(256, 4)
void pass_kernel(const _Float16* __restrict__ xh,
                 const _Float16* __restrict__ Wt,
                 const float* __restrict__ va,
                 const float* __restrict__ vb,
                 float* __restrict__ partials)      // [NCHK][B][C][L]
{
  __shared__ float red[3 * 16 * PADL];   // 31488 B: waves 1..3 stage sacc

  const int lane = threadIdx.x & 63;
  const int wid  = threadIdx.x >> 6;     // 4 waves split the n range
  const int bl   = lane & 15;            // batch (B/D col); cl row (A)
  const int hi   = lane >> 4;            // 0..3: k-quarter (A/B), l-quarter (D)
  const int b    = blockIdx.y * 16 + bl;
  const int n0   = blockIdx.x * TILE_B + wid * TILE_W;
  const int joff = (hi & 1) * 4;         // j-half within an n
  const int noff = (MODE == 0) ? (hi >> 1) : 0;   // MODE0: hi lanes carry n+1
  const bool lo  = lane < 32;

  h2 vvh[C_][2];                         // v[b][c][4*hi..+3] as packed f16
  if (MODE >= 1) {
#pragma unroll
    for (int c = 0; c < C_; ++c) {
      v4f t = *(const v4f*)(va + ((size_t)b * C_ + c) * L_ + hi * 4);
      if (MODE == 2)
        t += *(const v4f*)(vb + ((size_t)b * C_ + c) * L_ + hi * 4);
      vvh[c][0] = pkrtz(t[0], t[1]);
      vvh[c][1] = pkrtz(t[2], t[3]);
    }
  }

  const v4f zf = {0.f, 0.f, 0.f, 0.f};
  v4f sacc[C_];
#pragma unroll
  for (int c = 0; c < C_; ++c) sacc[c] = zf;

  const _Float16* xp = xh + ((size_t)b * N_ + n0 + noff) * 8 + joff;
  const _Float16* wp = Wt + ((size_t)(n0 + noff) * CL + bl) * 8 + joff;

  constexpr int NSTEP = (MODE == 0) ? 2 : 1;
  for (int nn = 0; nn < TILE_W; nn += NSTEP) {
    v4h xf = *(const v4h*)(xp + nn * 8);
    v4h wf[C_];
#pragma unroll
    for (int c = 0; c < C_; ++c)
      wf[c] = *(const v4h*)(wp + (size_t)nn * (CL * 8) + c * (16 * 8));

    if (MODE == 0) {
      // packed 2n per MFMA, all k real, accumulate straight into sacc
#pragma unroll
      for (int c = 0; c < C_; ++c)
        sacc[c] = __builtin_amdgcn_mfma_f32_16x16x16f16(wf[c], xf, sacc[c], 0, 0, 0);
    } else {
      v4h xm = xf;
      if (!lo) { v4h z = {}; xm = z; }   // zero k=8..15 via B fragment only

      // group 1: u per-c, folded into tt immediately (u never stored)
      float tt[C_];
#pragma unroll
      for (int c = 0; c < C_; ++c) {
        const v4f u = __builtin_amdgcn_mfma_f32_16x16x16f16(wf[c], xm, zf, 0, 0, 0);
        const h2 ua = pkrtz(u[0], u[1]);
        const h2 ub = pkrtz(u[2], u[3]);
        float t = fdot2(ua, vvh[c][0], 0.f);
        tt[c] = fdot2(ub, vvh[c][1], t);
      }
#pragma unroll
      for (int c = 0; c < C_; ++c) {
        tt[c] += __shfl_xor(tt[c], 16);
        tt[c] += __shfl_xor(tt[c], 32);
      }
#pragma unroll
      for (int c = 0; c < C_; ++c) tt[c] = __expf(tt[c]);
      // tree-sum the denominator (breaks the strict-fp serial add chain)
      float e01 = tt[0] + tt[1], e23 = tt[2] + tt[3];
      float e45 = tt[4] + tt[5], e67 = tt[6] + tt[7];
      float e89 = tt[8] + tt[9];
      const float es = ((e01 + e23) + (e45 + e67)) + e89;
      const float rs = __builtin_amdgcn_rcpf(es);

      // group 2: fold w[b,c] (per-lane == this lane's B column) into B
#pragma unroll
      for (int c = 0; c < C_; ++c) {
        const _Float16 wh = (_Float16)(tt[c] * rs);
        const v4h xw = xm * wh;
        sacc[c] = __builtin_amdgcn_mfma_f32_16x16x16f16(wf[c], xw, sacc[c], 0, 0, 0);
      }
    }
  }

  // cross-wave reduce: waves 1..3 stage, wave 0 sums and writes the chunk
  if (wid > 0) {
    float* dst = &red[(wid - 1) * 16 * PADL + bl * PADL];
#pragma unroll
    for (int c = 0; c < C_; ++c)
      *(v4f*)(dst + c * 16 + hi * 4) = sacc[c];
  }
  __syncthreads();
  if (wid == 0) {
    float* pout = partials + ((size_t)blockIdx.x * B_ + b) * CL + hi * 4;
#pragma unroll
    for (int c = 0; c < C_; ++c) {
      v4f a = sacc[c];
#pragma unroll
      for (int s = 0; s < 3; ++s)
        a += *(const v4f*)(&red[s * 16 * PADL + bl * PADL + c * 16 + hi * 4]);
      *(v4f*)(pout + c * L_) = a;
    }
  }
}

// Stage A: sum 192 chunks down to 16 groups (fully coalesced streaming)
__global__ __launch_bounds__(256)
void reduce_a(const float* __restrict__ p, float* __restrict__ p2) {
  const int t   = blockIdx.x * 256 + threadIdx.x;   // 0 .. 16*BCL-1
  const int idx = t % BCL;
  const int g   = t / BCL;
  float a = 0.f;
#pragma unroll
  for (int k = 0; k < RED_K; ++k)
    a += p[(size_t)(g * RED_K + k) * BCL + idx];
  p2[t] = a;
}

// Stage B: sum 16 groups, add bias, squash (16-lane shuffle for ||s||^2)
__global__ __launch_bounds__(256)
void reduce_b(const float* __restrict__ p2, const float* __restrict__ biases,
              float* __restrict__ vout, float scale) {
  const int idx = blockIdx.x * 256 + threadIdx.x;   // 0 .. BCL-1
  float a = 0.f;
#pragma unroll
  for (int g = 0; g < RED_G; ++g) a += p2[(size_t)g * BCL + idx];
  const float s = a * scale + biases[idx % CL];
  float n2 = s * s;
#pragma unroll
  for (int o = 8; o; o >>= 1) n2 += __shfl_xor(n2, o, 16);
  const float n = sqrtf(n2);
  const float f = n2 / ((1.f + n2) * (n + 1e-7f));
  vout[idx] = f * s;
}

extern "C" void kernel_launch(void* const* d_in, const int* in_sizes, int n_in,
                              void* d_out, int out_size, void* d_ws, size_t ws_size,
                              hipStream_t stream) {
  const float* x      = (const float*)d_in[0];
  const float* W      = (const float*)d_in[1];
  const float* biases = (const float*)d_in[2];
  float* out = (float*)d_out;

  _Float16* Wt  = (_Float16*)d_ws;                          // N*160*8 f16
  _Float16* xhp = Wt + (size_t)N_ * CL * 8 + 64;            // B*N*8 f16
  float* partials = (float*)(xhp + (size_t)B_ * N_ * 8 + 64);
  float* p2 = partials + (size_t)NCHK * BCL;
  float* v0 = p2 + (size_t)RED_G * BCL;
  float* v1 = v0 + BCL;

  conv_pack<<<WBLK + XBLK, 256, 0, stream>>>(W, x, (v8h*)Wt, (v8h*)xhp);

  const dim3 pg(NCHK, 8), pb(256);

  pass_kernel<0><<<pg, pb, 0, stream>>>(xhp, Wt, nullptr, nullptr, partials);
  reduce_a<<<(RED_G * BCL) / 256, 256, 0, stream>>>(partials, p2);
  reduce_b<<<BCL / 256, 256, 0, stream>>>(p2, biases, v0, 0.1f);

  pass_kernel<1><<<pg, pb, 0, stream>>>(xhp, Wt, v0, nullptr, partials);
  reduce_a<<<(RED_G * BCL) / 256, 256, 0, stream>>>(partials, p2);
  reduce_b<<<BCL / 256, 256, 0, stream>>>(p2, biases, v1, 1.0f);

  pass_kernel<2><<<pg, pb, 0, stream>>>(xhp, Wt, v0, v1, partials);
  reduce_a<<<(RED_G * BCL) / 256, 256, 0, stream>>>(partials, p2);
  reduce_b<<<BCL / 256, 256, 0, stream>>>(p2, biases, out, 1.0f);
}

// Round 8
// 173.772 us; speedup vs baseline: 1.0894x; 1.0894x over previous
//
#include <hip/hip_runtime.h>
#include <math.h>

// DigitCaps dynamic routing, MFMA version, round 8 (R7 + W-row addressing fix).
// u[b,n,cl] = sum_j x[b,n,j] W[n,j,cl] per-n on v_mfma_f32_16x16x16f16
//   (M=16: one capsule c's 16 l, N=16: batch, K=16; j=8 real).
// R7/R8 vs R5/R6: passes stuck at ~36-41us (issue bound ~5us) with all pipes
// idle -> exposed global-load latency on the 11 per-nn fragment loads.
// Fix: per-block async LDS staging with __builtin_amdgcn_global_load_lds
// (width=16: no VGPR destinations, 42 KiB in flight, ONE drain at the
// barrier), inner loop reads fragments via ds_read_b64 (<=2-way bank
// aliasing = free). R8 bug fix vs R7: w_lds row base is bl*8 (cl-offset
// within a capsule group), NOT (16*bl)*8 -- R7 read A rows at 16x the
// offset and failed absmax.
// Keeps: two-MFMA-group trick (u never stored; routing weight folded into
// B of group 2), tree-sum softmax denominator, MODE0 2-n-per-MFMA packing.

namespace {
constexpr int B_   = 128;
constexpr int N_   = 4608;
constexpr int C_   = 10;
constexpr int L_   = 16;
constexpr int CL   = C_ * L_;            // 160
constexpr int NCHK = 384;                // partial chunks (grid.x)
constexpr int TILE_N = N_ / NCHK;        // 12 n per block
constexpr int BCL  = B_ * CL;            // 20480
constexpr int RED_G = 16;
constexpr int RED_K = NCHK / RED_G;      // 24
constexpr int WBLK = (N_ * CL) / 256;    // 2880 blocks: W pack
constexpr int XBLK = (B_ * N_) / 256;    // 2304 blocks: x convert
constexpr int WI   = TILE_N * CL * 8 * 2 / 1024;  // 30 KiB-iters for W slab
constexpr int XI   = TILE_N * 64 * 8 * 2 / 1024;  // 12 KiB-iters for x slab
}

typedef _Float16 h2  __attribute__((ext_vector_type(2)));
typedef _Float16 v4h __attribute__((ext_vector_type(4)));
typedef _Float16 v8h __attribute__((ext_vector_type(8)));
typedef float    v4f __attribute__((ext_vector_type(4)));

__device__ inline h2 pkrtz(float a, float b) {
  return __builtin_bit_cast(h2, __builtin_amdgcn_cvt_pkrtz(a, b));
}

#if defined(__has_builtin)
#if __has_builtin(__builtin_amdgcn_fdot2)
#define HAVE_FDOT2 1
#endif
#endif

__device__ inline float fdot2(h2 a, h2 b, float c) {
#ifdef HAVE_FDOT2
  return __builtin_amdgcn_fdot2(a, b, c, false);
#else
  return c + (float)a[0] * (float)b[0] + (float)a[1] * (float)b[1];
#endif
}

// async 16B global -> LDS: lds base must be wave-uniform; HW adds lane*16.
#define GL2LDS(gsrc, ldsbase)                                               \
  __builtin_amdgcn_global_load_lds(                                         \
      (const __attribute__((address_space(1))) void*)(gsrc),                \
      (__attribute__((address_space(3))) void*)(ldsbase), 16, 0, 0)

// W [N][8][160] f32 -> Wt [N][160][8] f16 (transpose j<->cl, pack)
// x [B][N][8]  f32 -> xh [B][N][8]  f16 (straight convert)
__global__ __launch_bounds__(256)
void conv_pack(const float* __restrict__ W, const float* __restrict__ x,
               v8h* __restrict__ Wt, v8h* __restrict__ xh)
{
  if ((int)blockIdx.x < WBLK) {
    const int t  = blockIdx.x * 256 + threadIdx.x;     // (n, cl)
    const int n  = t / CL, cl = t % CL;
    const float* p = W + (size_t)n * (8 * CL) + cl;
    v8h o;
#pragma unroll
    for (int j = 0; j < 8; ++j) o[j] = (_Float16)p[j * CL];
    Wt[t] = o;
  } else {
    const int t = ((int)blockIdx.x - WBLK) * 256 + threadIdx.x; // 8-float chunk
    const float4 a = ((const float4*)x)[(size_t)t * 2 + 0];
    const float4 b = ((const float4*)x)[(size_t)t * 2 + 1];
    v8h o = { (_Float16)a.x, (_Float16)a.y, (_Float16)a.z, (_Float16)a.w,
              (_Float16)b.x, (_Float16)b.y, (_Float16)b.z, (_Float16)b.w };
    xh[t] = o;
  }
}

// MODE 0: uniform coupling (1/10 folded into reduce_b scale)
// MODE 1: logits t = u.v0      MODE 2: logits t = u.(v0+v1)
template<int MODE>
__global__ __launch_bounds__(256, 3)
void pass_kernel(const _Float16* __restrict__ xh,
                 const _Float16* __restrict__ Wt,
                 const float* __restrict__ va,
                 const float* __restrict__ vb,
                 float* __restrict__ partials)      // [NCHK][B][C][L]
{
  __shared__ __align__(16) _Float16 w_lds[TILE_N * CL * 8];  // 30720 B
  __shared__ __align__(16) _Float16 x_lds[TILE_N * 64 * 8];  // 12288 B

  const int lane = threadIdx.x & 63;
  const int wid  = threadIdx.x >> 6;     // 4 waves = 4 batch tiles of 16
  const int bl   = lane & 15;            // batch (B/D col); cl row (A)
  const int hi   = lane >> 4;            // 0..3: k-quarter (A/B), l-quarter (D)
  const int bbase = blockIdx.y * 64;
  const int b    = bbase + wid * 16 + bl;
  const int n0   = blockIdx.x * TILE_N;
  const int joff = (hi & 1) * 4;         // j-half within an n
  const int noff = (MODE == 0) ? (hi >> 1) : 0;   // MODE0: hi lanes carry n+1
  const bool lo  = lane < 32;

  // ---- async stage: W slab (30 KiB-iters) + x slab (12), striped by wave.
  // W slab is linear; x iter i2 fills x_lds[nn=i2][b=lane][8] from scattered
  // global addresses (per-lane gsrc is allowed; LDS side is linear).
  for (int i = wid; i < WI + XI; i += 4) {
    if (i < WI) {
      const _Float16* g = Wt + (size_t)n0 * CL * 8 + (size_t)i * 512 + lane * 8;
      GL2LDS(g, w_lds + i * 512);
    } else {
      const int i2 = i - WI;
      const _Float16* g = xh + ((size_t)(bbase + lane) * N_ + n0 + i2) * 8;
      GL2LDS(g, x_lds + i2 * 512);
    }
  }

  h2 vvh[C_][2];                         // v[b][c][4*hi..+3] as packed f16
  if (MODE >= 1) {
#pragma unroll
    for (int c = 0; c < C_; ++c) {
      v4f t = *(const v4f*)(va + ((size_t)b * C_ + c) * L_ + hi * 4);
      if (MODE == 2)
        t += *(const v4f*)(vb + ((size_t)b * C_ + c) * L_ + hi * 4);
      vvh[c][0] = pkrtz(t[0], t[1]);
      vvh[c][1] = pkrtz(t[2], t[3]);
    }
  }

  const v4f zf = {0.f, 0.f, 0.f, 0.f};
  v4f sacc[C_];
#pragma unroll
  for (int c = 0; c < C_; ++c) sacc[c] = zf;

  __syncthreads();                       // drains vmcnt (incl. LDS-DMA)

  const _Float16* xrow = x_lds + (wid * 16 + bl) * 8 + joff;  // + nn*64*8
  const _Float16* wrow = w_lds + bl * 8 + joff;               // + (nn*CL + c*16)*8

  constexpr int NSTEP = (MODE == 0) ? 2 : 1;
  for (int nn = 0; nn < TILE_N; nn += NSTEP) {
    const int na = nn + noff;
    v4h xf = *(const v4h*)(xrow + (size_t)na * (64 * 8));
    v4h wf[C_];
#pragma unroll
    for (int c = 0; c < C_; ++c)
      wf[c] = *(const v4h*)(wrow + ((size_t)na * CL + c * 16) * 8);

    if (MODE == 0) {
      // packed 2n per MFMA, all k real, accumulate straight into sacc
#pragma unroll
      for (int c = 0; c < C_; ++c)
        sacc[c] = __builtin_amdgcn_mfma_f32_16x16x16f16(wf[c], xf, sacc[c], 0, 0, 0);
    } else {
      v4h xm = xf;
      if (!lo) { v4h z = {}; xm = z; }   // zero k=8..15 via B fragment only

      // group 1: u per-c, folded into tt immediately (u never stored)
      float tt[C_];
#pragma unroll
      for (int c = 0; c < C_; ++c) {
        const v4f u = __builtin_amdgcn_mfma_f32_16x16x16f16(wf[c], xm, zf, 0, 0, 0);
        const h2 ua = pkrtz(u[0], u[1]);
        const h2 ub = pkrtz(u[2], u[3]);
        float t = fdot2(ua, vvh[c][0], 0.f);
        tt[c] = fdot2(ub, vvh[c][1], t);
      }
#pragma unroll
      for (int c = 0; c < C_; ++c) {
        tt[c] += __shfl_xor(tt[c], 16);
        tt[c] += __shfl_xor(tt[c], 32);
      }
#pragma unroll
      for (int c = 0; c < C_; ++c) tt[c] = __expf(tt[c]);
      // tree-sum the denominator (breaks the strict-fp serial add chain)
      float e01 = tt[0] + tt[1], e23 = tt[2] + tt[3];
      float e45 = tt[4] + tt[5], e67 = tt[6] + tt[7];
      float e89 = tt[8] + tt[9];
      const float es = ((e01 + e23) + (e45 + e67)) + e89;
      const float rs = __builtin_amdgcn_rcpf(es);

      // group 2: fold w[b,c] (per-lane == this lane's B column) into B
#pragma unroll
      for (int c = 0; c < C_; ++c) {
        const _Float16 wh = (_Float16)(tt[c] * rs);
        const v4h xw = xm * wh;
        sacc[c] = __builtin_amdgcn_mfma_f32_16x16x16f16(wf[c], xw, sacc[c], 0, 0, 0);
      }
    }
  }

  float* pout = partials + ((size_t)blockIdx.x * B_ + b) * CL + hi * 4;
#pragma unroll
  for (int c = 0; c < C_; ++c)
    *(v4f*)(pout + c * L_) = sacc[c];
}

// Stage A: sum 384 chunks down to 16 groups (fully coalesced streaming)
__global__ __launch_bounds__(256)
void reduce_a(const float* __restrict__ p, float* __restrict__ p2) {
  const int t   = blockIdx.x * 256 + threadIdx.x;   // 0 .. 16*BCL-1
  const int idx = t % BCL;
  const int g   = t / BCL;
  float a = 0.f;
#pragma unroll
  for (int k = 0; k < RED_K; ++k)
    a += p[(size_t)(g * RED_K + k) * BCL + idx];
  p2[t] = a;
}

// Stage B: sum 16 groups, add bias, squash (16-lane shuffle for ||s||^2)
__global__ __launch_bounds__(256)
void reduce_b(const float* __restrict__ p2, const float* __restrict__ biases,
              float* __restrict__ vout, float scale) {
  const int idx = blockIdx.x * 256 + threadIdx.x;   // 0 .. BCL-1
  float a = 0.f;
#pragma unroll
  for (int g = 0; g < RED_G; ++g) a += p2[(size_t)g * BCL + idx];
  const float s = a * scale + biases[idx % CL];
  float n2 = s * s;
#pragma unroll
  for (int o = 8; o; o >>= 1) n2 += __shfl_xor(n2, o, 16);
  const float n = sqrtf(n2);
  const float f = n2 / ((1.f + n2) * (n + 1e-7f));
  vout[idx] = f * s;
}

extern "C" void kernel_launch(void* const* d_in, const int* in_sizes, int n_in,
                              void* d_out, int out_size, void* d_ws, size_t ws_size,
                              hipStream_t stream) {
  const float* x      = (const float*)d_in[0];
  const float* W      = (const float*)d_in[1];
  const float* biases = (const float*)d_in[2];
  float* out = (float*)d_out;

  _Float16* Wt  = (_Float16*)d_ws;                          // N*160*8 f16
  _Float16* xhp = Wt + (size_t)N_ * CL * 8 + 64;            // B*N*8 f16
  float* partials = (float*)(xhp + (size_t)B_ * N_ * 8 + 64);
  float* p2 = partials + (size_t)NCHK * BCL;
  float* v0 = p2 + (size_t)RED_G * BCL;
  float* v1 = v0 + BCL;

  conv_pack<<<WBLK + XBLK, 256, 0, stream>>>(W, x, (v8h*)Wt, (v8h*)xhp);

  const dim3 pg(NCHK, 2), pb(256);

  pass_kernel<0><<<pg, pb, 0, stream>>>(xhp, Wt, nullptr, nullptr, partials);
  reduce_a<<<(RED_G * BCL) / 256, 256, 0, stream>>>(partials, p2);
  reduce_b<<<BCL / 256, 256, 0, stream>>>(p2, biases, v0, 0.1f);

  pass_kernel<1><<<pg, pb, 0, stream>>>(xhp, Wt, v0, nullptr, partials);
  reduce_a<<<(RED_G * BCL) / 256, 256, 0, stream>>>(partials, p2);
  reduce_b<<<BCL / 256, 256, 0, stream>>>(p2, biases, v1, 1.0f);

  pass_kernel<2><<<pg, pb, 0, stream>>>(xhp, Wt, v0, v1, partials);
  reduce_a<<<(RED_G * BCL) / 256, 256, 0, stream>>>(partials, p2);
  reduce_b<<<BCL / 256, 256, 0, stream>>>(p2, biases, out, 1.0f);
}